// Round 13
// baseline (181.664 us; speedup 1.0000x reference)
//
#include <hip/hip_runtime.h>

#define HW 36864            // 192*192
#define HDIM 192
#define NUNITS 8192         // 1024 windows * 8 heads
#define UPB 2               // units (waves) per block
#define UDW 2688            // LDS dwords per unit
#define QO 0
#define KO 768
#define VTO 1536
#define PO 0
// g-phase planes: wsP[g][head][dp][pix] as u32 (h2 pair). 4*8*12 = 384 planes.
#define P_BYTES (384ull * HW * 4)          // 56.6 MB

typedef __fp16 h2  __attribute__((ext_vector_type(2)));
typedef __fp16 v8h __attribute__((ext_vector_type(8)));
typedef float  v4f __attribute__((ext_vector_type(4)));

static __device__ __forceinline__ h2 pk2(float a, float b) {
    return __builtin_amdgcn_cvt_pkrtz(a, b);
}
static __device__ __forceinline__ unsigned h2u(h2 x) {
    union { h2 h; unsigned u; } c; c.h = x; return c.u;
}
static __device__ __forceinline__ h2 u2h(unsigned x) {
    union { unsigned u; h2 h; } c; c.u = x; return c.h;
}
static __device__ __forceinline__ v8h as_v8h(uint4 u) {
    union { uint4 u; v8h h; } c; c.u = u; return c.h;
}

// launch_bounds(128, 2): occupancy is LDS-bound (22.5KB -> 7 blocks/CU), so
// the min-waves bound is pure regalloc pressure. Cap 256 VGPR lets the
// scheduler keep more of the 72 independent gather loads in flight.
// VGPR_Count in the profile tells us whether the compiler took the headroom.
__global__ __launch_bounds__(128, 2)
void attn_mfma(const float* __restrict__ x,
               const float* __restrict__ fc,
               const float* __restrict__ wgt,
               float* __restrict__ out,        // used only in atomic fallback
               unsigned* __restrict__ wsP)     // may be null -> atomic fallback
{
    __shared__ unsigned lds[UPB * UDW];
    __shared__ float frs[64], fis[64];
    __shared__ unsigned zblk[4];

    const int wave = threadIdx.x >> 6;
    const int lane = threadIdx.x & 63;
    const int gid  = blockIdx.x * UPB + wave;
    const int head = gid & 7;
    const int wi   = gid >> 3;
    const int g    = wi & 3;
    const int iw   = (wi >> 2) & 15;
    const int ih   = wi >> 6;

    unsigned* uld = &lds[wave * UDW];

    if (threadIdx.x < 64) {
        float2 t = ((const float2*)fc)[threadIdx.x];
        frs[threadIdx.x] = t.x; fis[threadIdx.x] = t.y;
    } else if (threadIdx.x < 68) {
        zblk[threadIdx.x - 64] = 0;
    }
    // single barrier: covers frs/fis/zblk. Everything after this point is
    // intra-wave (per-wave LDS region), so the waves run fully decoupled.
    __syncthreads();

    // ---- phase 1: gather + PE + stage ----
    const int r = lane >> 3, col = lane & 7;
    const int h0 = ih * 12 + r, w0 = iw * 12 + col;
    int in_h = h0 + ((g & 1) ? 6 : 0); if (in_h >= HDIM) in_h = 2 * HDIM - 2 - in_h;
    int in_w = w0 + ((g & 2) ? 6 : 0); if (in_w >= HDIM) in_w = 2 * HDIM - 2 - in_w;

    float q[24], k[24], v[24];
    {
        // direct f32 gather: lanes = 8 rows x 8 cols of the window; each load
        // is 8 contiguous 32B row-segments; x (85 MB) << LLC so the 4x window
        // overlap is cache-served.
        const float* xb = x + (size_t)(head * 24) * HW + in_h * HDIM + in_w;
#pragma unroll
        for (int dd = 0; dd < 24; ++dd) q[dd] = xb[(size_t)dd * HW];
#pragma unroll
        for (int dd = 0; dd < 24; ++dd) k[dd] = xb[(size_t)dd * HW + (size_t)192 * HW];
#pragma unroll
        for (int dd = 0; dd < 24; ++dd) v[dd] = xb[(size_t)dd * HW + (size_t)384 * HW];
    }

#pragma unroll
    for (int p = 0; p < 8; ++p) {
        const float frr = frs[r * 8 + p],   fir = fis[r * 8 + p];
        const float frc = frs[col * 8 + p], fic = fis[col * 8 + p];
        {
            float a = q[3*p], b = q[3*p+1], c3 = q[3*p+2];
            float b2 = a * fir + b * frr;
            q[3*p]   = a * frr - b * fir;
            q[3*p+1] = b2 * frc - c3 * fic;
            q[3*p+2] = b2 * fic + c3 * frc;
        }
        {
            float a = k[3*p], b = k[3*p+1], c3 = k[3*p+2];
            float b2 = a * fir + b * frr;
            k[3*p]   = a * frr - b * fir;
            k[3*p+1] = b2 * frc - c3 * fic;
            k[3*p+2] = b2 * fic + c3 * frc;
        }
    }

    {
        // log2(e)/sqrt(24): folds the exp->exp2 conversion into the Q scale
        const float sc = 0.29448903f;
        uint2* qw = (uint2*)&uld[QO + lane * 12];
        uint2* kw = (uint2*)&uld[KO + lane * 12];
#pragma unroll
        for (int j = 0; j < 3; ++j) {
            qw[2*j]   = make_uint2(h2u(pk2(q[8*j]*sc,   q[8*j+1]*sc)),
                                   h2u(pk2(q[8*j+2]*sc, q[8*j+3]*sc)));
            qw[2*j+1] = make_uint2(h2u(pk2(q[8*j+4]*sc, q[8*j+5]*sc)),
                                   h2u(pk2(q[8*j+6]*sc, q[8*j+7]*sc)));
            kw[2*j]   = make_uint2(h2u(pk2(k[8*j],   k[8*j+1])),
                                   h2u(pk2(k[8*j+2], k[8*j+3])));
            kw[2*j+1] = make_uint2(h2u(pk2(k[8*j+4], k[8*j+5])),
                                   h2u(pk2(k[8*j+6], k[8*j+7])));
        }
    }
    {
#pragma unroll
        for (int i = 0; i < 5; ++i) {           // zero V^T rows 24..31
            int idx = lane + i * 64;
            if (idx < 288) uld[VTO + 24 * 36 + idx] = 0;
        }
        __fp16* vt = (__fp16*)&uld[VTO];
        vt[24 * 72 + lane] = (__fp16)1.0f;      // ones row -> denominators
#pragma unroll
        for (int dd = 0; dd < 24; ++dd) vt[dd * 72 + lane] = (__fp16)v[dd];
    }
    // intra-wave LDS RAW only past this point: compiler-level fence is enough
    // (same mechanism the P-store -> P-read path already relies on).
    asm volatile("" ::: "memory");

    // ---- phase 2 ----
    const int qq = lane >> 4, l15 = lane & 15;
    v8h Qf[4], Kf[4];
#pragma unroll
    for (int t = 0; t < 4; ++t) {
        const unsigned* qa = (qq < 3) ? &uld[QO + (16*t + l15)*12 + 4*qq] : zblk;
        const unsigned* ka = (qq < 3) ? &uld[KO + (16*t + l15)*12 + 4*qq] : zblk;
        Qf[t] = as_v8h(*(const uint4*)qa);
        Kf[t] = as_v8h(*(const uint4*)ka);
    }
    v8h Vf[2][2];
#pragma unroll
    for (int dt = 0; dt < 2; ++dt)
#pragma unroll
        for (int ks = 0; ks < 2; ++ks)
            Vf[dt][ks] = as_v8h(*(const uint4*)&uld[VTO + (16*dt + l15)*36 + 16*ks + 4*qq]);

    // Swapped-operand QK^T: mfma(K,Q) gives S^T, so each lane's 4 accumulator
    // rows are 4 CONSECUTIVE key positions at a fixed query column -> pack
    // exp2'd P as two h2 pairs and store with ONE ds_write_b64.
#pragma unroll
    for (int tn = 0; tn < 4; ++tn) {
#pragma unroll
        for (int tm = 0; tm < 4; ++tm) {
            v4f c = {0.f, 0.f, 0.f, 0.f};
            c = __builtin_amdgcn_mfma_f32_16x16x32_f16(Kf[tn], Qf[tm], c, 0, 0, 0);
            // P[query = 16*tm + l15][key = 16*tn + 4*qq + rg]
            uint2 w = make_uint2(h2u(pk2(__builtin_amdgcn_exp2f(c[0]),
                                         __builtin_amdgcn_exp2f(c[1]))),
                                 h2u(pk2(__builtin_amdgcn_exp2f(c[2]),
                                         __builtin_amdgcn_exp2f(c[3]))));
            *(uint2*)&uld[PO + (16*tm + l15)*36 + 8*tn + 2*qq] = w;
        }
    }

    v4f O[2][4];
#pragma unroll
    for (int dt = 0; dt < 2; ++dt)
#pragma unroll
        for (int lt = 0; lt < 4; ++lt)
            O[dt][lt] = (v4f){0.f, 0.f, 0.f, 0.f};
#pragma unroll
    for (int lt = 0; lt < 4; ++lt) {
#pragma unroll
        for (int ks = 0; ks < 2; ++ks) {
            v8h Pf = as_v8h(*(const uint4*)&uld[PO + (16*lt + l15)*36 + 16*ks + 4*qq]);
            O[0][lt] = __builtin_amdgcn_mfma_f32_16x16x32_f16(Vf[0][ks], Pf, O[0][lt], 0, 0, 0);
            O[1][lt] = __builtin_amdgcn_mfma_f32_16x16x32_f16(Vf[1][ks], Pf, O[1][lt], 0, 0, 0);
        }
    }

    float inv[4];
#pragma unroll
    for (int lt = 0; lt < 4; ++lt)
        inv[lt] = 1.0f / __shfl(O[1][lt][0], 32 + l15, 64);

    if (wsP) {
        // g-phase-plane epilogue: same-phase windows never overlap, so each
        // wave scatters its normalized O (h2 pairs) straight to output coords
        // within its phase plane; merge then reads fully coalesced.
        const int goffh = (g & 1) ? 6 : 0, goffw = (g & 2) ? 6 : 0;
        unsigned* pb = wsP + (size_t)((g * 8 + head) * 12) * HW;
#pragma unroll
        for (int lt = 0; lt < 4; ++lt) {
            const int l  = 16*lt + l15;
            const int oh = ih * 12 + (l >> 3) + goffh;
            const int ow = iw * 12 + (l & 7)  + goffw;
            if (oh < HDIM && ow < HDIM) {
                const float  sc = inv[lt];
                const size_t o  = (size_t)oh * HDIM + ow;
                pb[(size_t)(2*qq+0) * HW + o] = h2u(pk2(O[0][lt][0]*sc, O[0][lt][1]*sc));
                pb[(size_t)(2*qq+1) * HW + o] = h2u(pk2(O[0][lt][2]*sc, O[0][lt][3]*sc));
                if (qq < 2) {
                    pb[(size_t)(8+2*qq) * HW + o] = h2u(pk2(O[1][lt][0]*sc, O[1][lt][1]*sc));
                    pb[(size_t)(9+2*qq) * HW + o] = h2u(pk2(O[1][lt][2]*sc, O[1][lt][3]*sc));
                }
            }
        }
    } else {
        // atomic fallback
#pragma unroll
        for (int lt = 0; lt < 4; ++lt) {
            const int l  = 16*lt + l15;
            const int oh = ih * 12 + (l >> 3) + ((g & 1) ? 6 : 0);
            const int ow = iw * 12 + (l & 7)  + ((g & 2) ? 6 : 0);
            if (oh < HDIM && ow < HDIM) {
                const float sc = inv[lt] / wgt[oh * HDIM + ow];
                float* ob = out + (size_t)(head * 24) * HW + oh * HDIM + ow;
#pragma unroll
                for (int rg = 0; rg < 4; ++rg)
                    atomicAdd(ob + (size_t)(4*qq + rg) * HW, O[0][lt][rg] * sc);
                if (qq < 2) {
#pragma unroll
                    for (int rg = 0; rg < 4; ++rg)
                        atomicAdd(ob + (size_t)(16 + 4*qq + rg) * HW, O[1][lt][rg] * sc);
                }
            }
        }
    }
}

// ---- phase B: overlap-add merge, streaming. Thread = (head,dp) x 2 pixels.
// Reads the SAME pix offset in <=4 g-planes (coalesced uint2), predicated by
// the %12 window-coverage mask; no gathers, no per-unit index math.
__global__ __launch_bounds__(256)
void merge_out(const unsigned* __restrict__ wsP,
               const float* __restrict__ wgt,
               float* __restrict__ out)
{
    const int idx = blockIdx.x * 256 + threadIdx.x;    // grid exact: 96*HW/2
    const int pp  = idx / (HW / 2);                    // 0..95 = head*12 + dp
    const int px2 = idx - pp * (HW / 2);
    const int pix = 2 * px2;
    const int h   = px2 / (HDIM / 2);
    const int w   = pix - h * HDIM;                    // even, pair is (w, w+1)
    const int head = pp / 12;
    const int dp   = pp - head * 12;

    // coverage masks: phase offset 0 valid iff coord%12 < 8;
    // offset 6 valid iff coord>=6 && (coord-6)%12 < 8.
    const int hm = h % 12;
    const bool vh0 = hm < 8;
    int hm6 = hm + 6; if (hm6 >= 12) hm6 -= 12;
    const bool vh1 = (h >= 6) && (hm6 < 8);

    const int wm = w % 12;
    const bool vw0a = wm < 8;
    const int wmb = (wm == 11) ? 0 : wm + 1;
    const bool vw0b = wmb < 8;
    int wm6 = wm + 6; if (wm6 >= 12) wm6 -= 12;
    const bool vw1a = (w >= 6) && (wm6 < 8);
    const int wm6b = (wm6 == 11) ? 0 : wm6 + 1;
    const bool vw1b = (w + 1 >= 6) && (wm6b < 8);

    float a0 = 0.f, a1 = 0.f, b0 = 0.f, b1 = 0.f;
#pragma unroll
    for (int g = 0; g < 4; ++g) {
        const bool vh = (g & 1) ? vh1 : vh0;
        const bool va = vh && ((g & 2) ? vw1a : vw0a);
        const bool vb = vh && ((g & 2) ? vw1b : vw0b);
        if (va || vb) {
            const uint2 u = *(const uint2*)&wsP[(size_t)(g * 96 + pp) * HW + pix];
            if (va) { h2 t = u2h(u.x); a0 += (float)t[0]; a1 += (float)t[1]; }
            if (vb) { h2 t = u2h(u.y); b0 += (float)t[0]; b1 += (float)t[1]; }
        }
    }
    const float2 wv = *(const float2*)&wgt[pix];
    const size_t c0 = (size_t)(head * 24 + 2 * dp) * HW + pix;
    *(float2*)&out[c0]      = make_float2(a0 / wv.x, b0 / wv.y);
    *(float2*)&out[c0 + HW] = make_float2(a1 / wv.x, b1 / wv.y);
}

extern "C" void kernel_launch(void* const* d_in, const int* in_sizes, int n_in,
                              void* d_out, int out_size, void* d_ws, size_t ws_size,
                              hipStream_t stream) {
    const float* x   = (const float*)d_in[0];
    const float* fc  = (const float*)d_in[1];
    const float* wgt = (const float*)d_in[2];
    float* out = (float*)d_out;

    unsigned* wsP = ws_size >= P_BYTES ? (unsigned*)d_ws : nullptr;

    if (!wsP)
        (void)hipMemsetAsync(out, 0, (size_t)out_size * sizeof(float), stream);
    attn_mfma<<<NUNITS / UPB, UPB * 64, 0, stream>>>(x, fc, wgt, out, wsP);
    if (wsP)
        merge_out<<<96 * (HW / 2) / 256, 256, 0, stream>>>(wsP, wgt, out);
}

// Round 15
// 177.983 us; speedup vs baseline: 1.0207x; 1.0207x over previous
//
#include <hip/hip_runtime.h>

#define HW 36864            // 192*192
#define HDIM 192
#define NUNITS 8192         // 1024 windows * 8 heads
#define UPB 2               // units (waves) per block
#define UDW 2688            // LDS dwords per unit
#define QO 0
#define KO 768
#define VTO 1536
#define PO 0
// g-phase planes, pixel-major: wsP[((g*8+head)*HW + pix)*12 + dp] as u32 (h2).
// 48B per pixel -> attn writes 384B row-runs, merge reads 48B/pixel coalesced.
#define P_BYTES (384ull * HW * 4)          // 56.6 MB (4*8*12 planes equivalent)

typedef __fp16 h2  __attribute__((ext_vector_type(2)));
typedef __fp16 v8h __attribute__((ext_vector_type(8)));
typedef float  v4f __attribute__((ext_vector_type(4)));

static __device__ __forceinline__ h2 pk2(float a, float b) {
    return __builtin_amdgcn_cvt_pkrtz(a, b);
}
static __device__ __forceinline__ unsigned h2u(h2 x) {
    union { h2 h; unsigned u; } c; c.h = x; return c.u;
}
static __device__ __forceinline__ h2 u2h(unsigned x) {
    union { unsigned u; h2 h; } c; c.u = x; return c.h;
}
static __device__ __forceinline__ v8h as_v8h(uint4 u) {
    union { uint4 u; v8h h; } c; c.u = u; return c.h;
}

// launch_bounds(128,2): proven neutral in R13 (VGPR stayed 60) — kept so this
// round's delta attributes purely to the epilogue/merge layout change.
__global__ __launch_bounds__(128, 2)
void attn_mfma(const float* __restrict__ x,
               const float* __restrict__ fc,
               const float* __restrict__ wgt,
               float* __restrict__ out,        // used only in atomic fallback
               unsigned* __restrict__ wsP)     // may be null -> atomic fallback
{
    __shared__ unsigned lds[UPB * UDW];
    __shared__ float frs[64], fis[64];
    __shared__ unsigned zblk[4];

    const int wave = threadIdx.x >> 6;
    const int lane = threadIdx.x & 63;
    const int gid  = blockIdx.x * UPB + wave;
    const int head = gid & 7;
    const int wi   = gid >> 3;
    const int g    = wi & 3;
    const int iw   = (wi >> 2) & 15;
    const int ih   = wi >> 6;

    unsigned* uld = &lds[wave * UDW];

    if (threadIdx.x < 64) {
        float2 t = ((const float2*)fc)[threadIdx.x];
        frs[threadIdx.x] = t.x; fis[threadIdx.x] = t.y;
    } else if (threadIdx.x < 68) {
        zblk[threadIdx.x - 64] = 0;
    }
    // single barrier: covers frs/fis/zblk. Everything after this point is
    // intra-wave (per-wave LDS region), so the waves run fully decoupled.
    __syncthreads();

    // ---- phase 1: gather + PE + stage ----
    const int r = lane >> 3, col = lane & 7;
    const int h0 = ih * 12 + r, w0 = iw * 12 + col;
    int in_h = h0 + ((g & 1) ? 6 : 0); if (in_h >= HDIM) in_h = 2 * HDIM - 2 - in_h;
    int in_w = w0 + ((g & 2) ? 6 : 0); if (in_w >= HDIM) in_w = 2 * HDIM - 2 - in_w;

    float q[24], k[24], v[24];
    {
        // direct f32 gather: lanes = 8 rows x 8 cols of the window; each load
        // is 8 contiguous 32B row-segments; x (85 MB) << LLC so the 4x window
        // overlap is cache-served.
        const float* xb = x + (size_t)(head * 24) * HW + in_h * HDIM + in_w;
#pragma unroll
        for (int dd = 0; dd < 24; ++dd) q[dd] = xb[(size_t)dd * HW];
#pragma unroll
        for (int dd = 0; dd < 24; ++dd) k[dd] = xb[(size_t)dd * HW + (size_t)192 * HW];
#pragma unroll
        for (int dd = 0; dd < 24; ++dd) v[dd] = xb[(size_t)dd * HW + (size_t)384 * HW];
    }

#pragma unroll
    for (int p = 0; p < 8; ++p) {
        const float frr = frs[r * 8 + p],   fir = fis[r * 8 + p];
        const float frc = frs[col * 8 + p], fic = fis[col * 8 + p];
        {
            float a = q[3*p], b = q[3*p+1], c3 = q[3*p+2];
            float b2 = a * fir + b * frr;
            q[3*p]   = a * frr - b * fir;
            q[3*p+1] = b2 * frc - c3 * fic;
            q[3*p+2] = b2 * fic + c3 * frc;
        }
        {
            float a = k[3*p], b = k[3*p+1], c3 = k[3*p+2];
            float b2 = a * fir + b * frr;
            k[3*p]   = a * frr - b * fir;
            k[3*p+1] = b2 * frc - c3 * fic;
            k[3*p+2] = b2 * fic + c3 * frc;
        }
    }

    {
        // log2(e)/sqrt(24): folds the exp->exp2 conversion into the Q scale
        const float sc = 0.29448903f;
        uint2* qw = (uint2*)&uld[QO + lane * 12];
        uint2* kw = (uint2*)&uld[KO + lane * 12];
#pragma unroll
        for (int j = 0; j < 3; ++j) {
            qw[2*j]   = make_uint2(h2u(pk2(q[8*j]*sc,   q[8*j+1]*sc)),
                                   h2u(pk2(q[8*j+2]*sc, q[8*j+3]*sc)));
            qw[2*j+1] = make_uint2(h2u(pk2(q[8*j+4]*sc, q[8*j+5]*sc)),
                                   h2u(pk2(q[8*j+6]*sc, q[8*j+7]*sc)));
            kw[2*j]   = make_uint2(h2u(pk2(k[8*j],   k[8*j+1])),
                                   h2u(pk2(k[8*j+2], k[8*j+3])));
            kw[2*j+1] = make_uint2(h2u(pk2(k[8*j+4], k[8*j+5])),
                                   h2u(pk2(k[8*j+6], k[8*j+7])));
        }
    }
    {
#pragma unroll
        for (int i = 0; i < 5; ++i) {           // zero V^T rows 24..31
            int idx = lane + i * 64;
            if (idx < 288) uld[VTO + 24 * 36 + idx] = 0;
        }
        __fp16* vt = (__fp16*)&uld[VTO];
        vt[24 * 72 + lane] = (__fp16)1.0f;      // ones row -> denominators
#pragma unroll
        for (int dd = 0; dd < 24; ++dd) vt[dd * 72 + lane] = (__fp16)v[dd];
    }
    // intra-wave LDS RAW only past this point: compiler-level fence is enough
    // (same mechanism the P-store -> P-read path already relies on).
    asm volatile("" ::: "memory");

    // ---- phase 2 ----
    const int qq = lane >> 4, l15 = lane & 15;
    v8h Qf[4], Kf[4];
#pragma unroll
    for (int t = 0; t < 4; ++t) {
        const unsigned* qa = (qq < 3) ? &uld[QO + (16*t + l15)*12 + 4*qq] : zblk;
        const unsigned* ka = (qq < 3) ? &uld[KO + (16*t + l15)*12 + 4*qq] : zblk;
        Qf[t] = as_v8h(*(const uint4*)qa);
        Kf[t] = as_v8h(*(const uint4*)ka);
    }
    v8h Vf[2][2];
#pragma unroll
    for (int dt = 0; dt < 2; ++dt)
#pragma unroll
        for (int ks = 0; ks < 2; ++ks)
            Vf[dt][ks] = as_v8h(*(const uint4*)&uld[VTO + (16*dt + l15)*36 + 16*ks + 4*qq]);

    // Swapped-operand QK^T: mfma(K,Q) gives S^T, so each lane's 4 accumulator
    // rows are 4 CONSECUTIVE key positions at a fixed query column -> pack
    // exp2'd P as two h2 pairs and store with ONE ds_write_b64.
#pragma unroll
    for (int tn = 0; tn < 4; ++tn) {
#pragma unroll
        for (int tm = 0; tm < 4; ++tm) {
            v4f c = {0.f, 0.f, 0.f, 0.f};
            c = __builtin_amdgcn_mfma_f32_16x16x32_f16(Kf[tn], Qf[tm], c, 0, 0, 0);
            // P[query = 16*tm + l15][key = 16*tn + 4*qq + rg]
            uint2 w = make_uint2(h2u(pk2(__builtin_amdgcn_exp2f(c[0]),
                                         __builtin_amdgcn_exp2f(c[1]))),
                                 h2u(pk2(__builtin_amdgcn_exp2f(c[2]),
                                         __builtin_amdgcn_exp2f(c[3]))));
            *(uint2*)&uld[PO + (16*tm + l15)*36 + 8*tn + 2*qq] = w;
        }
    }

    v4f O[2][4];
#pragma unroll
    for (int dt = 0; dt < 2; ++dt)
#pragma unroll
        for (int lt = 0; lt < 4; ++lt)
            O[dt][lt] = (v4f){0.f, 0.f, 0.f, 0.f};
#pragma unroll
    for (int lt = 0; lt < 4; ++lt) {
#pragma unroll
        for (int ks = 0; ks < 2; ++ks) {
            v8h Pf = as_v8h(*(const uint4*)&uld[PO + (16*lt + l15)*36 + 16*ks + 4*qq]);
            O[0][lt] = __builtin_amdgcn_mfma_f32_16x16x32_f16(Vf[0][ks], Pf, O[0][lt], 0, 0, 0);
            O[1][lt] = __builtin_amdgcn_mfma_f32_16x16x32_f16(Vf[1][ks], Pf, O[1][lt], 0, 0, 0);
        }
    }

    float inv[4];
#pragma unroll
    for (int lt = 0; lt < 4; ++lt)
        inv[lt] = 1.0f / __shfl(O[1][lt][0], 32 + l15, 64);

    if (wsP) {
        // Pixel-major epilogue: stage normalized h2 into LDS sm[pixel][dp]
        // (768 dw; reuses the per-wave region — P/Q/K/VT all dead after PV),
        // then lane = pixel writes its 48B (3x uint4) -> 384B row-runs.
        unsigned* sm = uld;
        asm volatile("" ::: "memory");
#pragma unroll
        for (int lt = 0; lt < 4; ++lt) {
            const int   l  = 16*lt + l15;
            const float sc = inv[lt];
            sm[l*12 + 2*qq]     = h2u(pk2(O[0][lt][0]*sc, O[0][lt][1]*sc));
            sm[l*12 + 2*qq + 1] = h2u(pk2(O[0][lt][2]*sc, O[0][lt][3]*sc));
            if (qq < 2) {
                sm[l*12 + 8 + 2*qq] = h2u(pk2(O[1][lt][0]*sc, O[1][lt][1]*sc));
                sm[l*12 + 9 + 2*qq] = h2u(pk2(O[1][lt][2]*sc, O[1][lt][3]*sc));
            }
        }
        asm volatile("" ::: "memory");
        const int goffh = (g & 1) ? 6 : 0, goffw = (g & 2) ? 6 : 0;
        const int oh = ih * 12 + (lane >> 3) + goffh;
        const int ow = iw * 12 + (lane & 7)  + goffw;
        if (oh < HDIM && ow < HDIM) {
            uint4* dst = (uint4*)&wsP[((size_t)(g * 8 + head) * HW
                                       + (size_t)oh * HDIM + ow) * 12];
            const uint4* src = (const uint4*)&sm[lane * 12];
            dst[0] = src[0]; dst[1] = src[1]; dst[2] = src[2];
        }
    } else {
        // atomic fallback
#pragma unroll
        for (int lt = 0; lt < 4; ++lt) {
            const int l  = 16*lt + l15;
            const int oh = ih * 12 + (l >> 3) + ((g & 1) ? 6 : 0);
            const int ow = iw * 12 + (l & 7)  + ((g & 2) ? 6 : 0);
            if (oh < HDIM && ow < HDIM) {
                const float sc = inv[lt] / wgt[oh * HDIM + ow];
                float* ob = out + (size_t)(head * 24) * HW + oh * HDIM + ow;
#pragma unroll
                for (int rg = 0; rg < 4; ++rg)
                    atomicAdd(ob + (size_t)(4*qq + rg) * HW, O[0][lt][rg] * sc);
                if (qq < 2) {
#pragma unroll
                    for (int rg = 0; rg < 4; ++rg)
                        atomicAdd(ob + (size_t)(16 + 4*qq + rg) * HW, O[1][lt][rg] * sc);
                }
            }
        }
    }
}

// ---- phase B: overlap-add merge. Thread = (head, pixel), all 24 channels.
// Reads the pixel's 48B (3x uint4) from each covering phase (<=4, predicated
// by the %12 coverage test), accumulates in registers, then writes 24
// fully-coalesced channel stores (256B/instruction across the wave).
__global__ __launch_bounds__(256)
void merge_out(const unsigned* __restrict__ wsP,
               const float* __restrict__ wgt,
               float* __restrict__ out)
{
    const int idx  = blockIdx.x * 256 + threadIdx.x;   // grid exact: 8*HW
    const int head = idx / HW;
    const int pix  = idx - head * HW;
    const int h    = pix / HDIM;
    const int w    = pix - h * HDIM;

    float acc[24];
#pragma unroll
    for (int d = 0; d < 24; ++d) acc[d] = 0.f;

#pragma unroll
    for (int g = 0; g < 4; ++g) {
        const int hh = h - ((g & 1) ? 6 : 0);
        const int ww = w - ((g & 2) ? 6 : 0);
        if (hh < 0 || ww < 0) continue;
        if (hh % 12 >= 8 || ww % 12 >= 8) continue;
        const uint4* src = (const uint4*)&wsP[((size_t)(g * 8 + head) * HW + pix) * 12];
#pragma unroll
        for (int j = 0; j < 3; ++j) {
            const uint4 u = src[j];
#pragma unroll
            for (int t = 0; t < 4; ++t) {
                const h2 p = u2h(((const unsigned*)&u)[t]);
                acc[8*j + 2*t]     += (float)p[0];
                acc[8*j + 2*t + 1] += (float)p[1];
            }
        }
    }
    const float wv = wgt[pix];
#pragma unroll
    for (int d = 0; d < 24; ++d)
        out[(size_t)(head * 24 + d) * HW + pix] = acc[d] / wv;
}

extern "C" void kernel_launch(void* const* d_in, const int* in_sizes, int n_in,
                              void* d_out, int out_size, void* d_ws, size_t ws_size,
                              hipStream_t stream) {
    const float* x   = (const float*)d_in[0];
    const float* fc  = (const float*)d_in[1];
    const float* wgt = (const float*)d_in[2];
    float* out = (float*)d_out;

    unsigned* wsP = ws_size >= P_BYTES ? (unsigned*)d_ws : nullptr;

    if (!wsP)
        (void)hipMemsetAsync(out, 0, (size_t)out_size * sizeof(float), stream);
    attn_mfma<<<NUNITS / UPB, UPB * 64, 0, stream>>>(x, fc, wgt, out, wsP);
    if (wsP)
        merge_out<<<8 * HW / 256, 256, 0, stream>>>(wsP, wgt, out);
}

// Round 17
// 173.995 us; speedup vs baseline: 1.0441x; 1.0229x over previous
//
#include <hip/hip_runtime.h>

#define HW 36864            // 192*192
#define HDIM 192
#define NUNITS 8192         // 1024 windows * 8 heads
#define RDW 4608            // raw LDS region: 72ch * 64 dw (f32 window tile)
#define QO 0
#define KO 768
#define VTO 1536
#define PO 0
// g-phase planes, pixel-major: wsP[((g*8+head)*HW + pix)*12 + dp] as u32 (h2).
#define P_BYTES (384ull * HW * 4)          // 56.6 MB

typedef __fp16 h2  __attribute__((ext_vector_type(2)));
typedef __fp16 v8h __attribute__((ext_vector_type(8)));
typedef float  v4f __attribute__((ext_vector_type(4)));

static __device__ __forceinline__ h2 pk2(float a, float b) {
    return __builtin_amdgcn_cvt_pkrtz(a, b);
}
static __device__ __forceinline__ unsigned h2u(h2 x) {
    union { h2 h; unsigned u; } c; c.h = x; return c.u;
}
static __device__ __forceinline__ h2 u2h(unsigned x) {
    union { unsigned u; h2 h; } c; c.u = x; return c.h;
}
static __device__ __forceinline__ v8h as_v8h(uint4 u) {
    union { uint4 u; v8h h; } c; c.u = u; return c.h;
}

// One wave per block (64 threads). LDS: raw 18KB overlaid by fragments+P.
// 19KB/block -> 8 blocks/CU. Cooperative float4 gather replaces 72
// near-serial scalar loads (the measured 38K-cycle latency wall).
__global__ __launch_bounds__(64)
void attn_mfma(const float* __restrict__ x,
               const float* __restrict__ fc,
               const float* __restrict__ wgt,
               float* __restrict__ out,        // used only in atomic fallback
               unsigned* __restrict__ wsP)     // may be null -> atomic fallback
{
    __shared__ unsigned lds[RDW];
    __shared__ float frs[64], fis[64];
    __shared__ unsigned zblk[4];

    const int lane = threadIdx.x;
    const int gid  = blockIdx.x;
    const int head = gid & 7;
    const int wi   = gid >> 3;
    const int g    = wi & 3;
    const int iw   = (wi >> 2) & 15;
    const int ih   = wi >> 6;

    unsigned* uld = lds;

    {
        float2 t = ((const float2*)fc)[lane];
        frs[lane] = t.x; fis[lane] = t.y;
        if (lane < 4) zblk[lane] = 0;
    }
    __syncthreads();   // single wave: near-free; orders frs/fis/zblk

    // ---- phase 1: cooperative gather + PE + stage ----
    const int r = lane >> 3, col = lane & 7;
    const int h0 = ih * 12 + r, w0 = iw * 12 + col;
    int in_h = h0 + ((g & 1) ? 6 : 0); if (in_h >= HDIM) in_h = 2 * HDIM - 2 - in_h;
    int in_w = w0 + ((g & 2) ? 6 : 0); if (in_w >= HDIM) in_w = 2 * HDIM - 2 - in_w;

    float q[24], k[24], v[24];
    const bool wrefl = (g & 2) && (iw == 15);   // w-reflection breaks 16B spans (~3% of units)
    if (!wrefl) {
        // lane -> (ch4 = lane>>4 of 4 channels/issue, row = (lane&15)>>1, half = lane&1)
        const int ch4  = lane >> 4;
        const int row  = (lane & 15) >> 1;
        const int half = lane & 1;
        int rh = ih * 12 + row + ((g & 1) ? 6 : 0);
        if (rh >= HDIM) rh = 2 * HDIM - 2 - rh;          // per-row h-reflection ok
        const int wb = iw * 12 + ((g & 2) ? 6 : 0);       // no w-reflection on fast path
        const size_t rowoff = (size_t)rh * HDIM + wb + half * 4;
        unsigned* dst0 = &lds[ch4 * 64 + row * 8 + half * 4];
#pragma unroll
        for (int i = 0; i < 18; ++i) {
            const int c72 = i * 4 + ch4;                  // 0..71
            const int qkv = c72 / 24, dd = c72 - qkv * 24;
            const float* src = x + (size_t)(qkv * 192 + head * 24 + dd) * HW + rowoff;
            *(uint4*)(dst0 + (size_t)i * 256) = *(const uint4*)src;
        }
        asm volatile("" ::: "memory");
        // per-lane pull: R[ch][lane] -> 2 lanes/bank (free)
        const float* Rf = (const float*)lds;
#pragma unroll
        for (int dd = 0; dd < 24; ++dd) q[dd] = Rf[dd * 64 + lane];
#pragma unroll
        for (int dd = 0; dd < 24; ++dd) k[dd] = Rf[(24 + dd) * 64 + lane];
#pragma unroll
        for (int dd = 0; dd < 24; ++dd) v[dd] = Rf[(48 + dd) * 64 + lane];
    } else {
        const float* xb = x + (size_t)(head * 24) * HW + in_h * HDIM + in_w;
#pragma unroll
        for (int dd = 0; dd < 24; ++dd) q[dd] = xb[(size_t)dd * HW];
#pragma unroll
        for (int dd = 0; dd < 24; ++dd) k[dd] = xb[(size_t)dd * HW + (size_t)192 * HW];
#pragma unroll
        for (int dd = 0; dd < 24; ++dd) v[dd] = xb[(size_t)dd * HW + (size_t)384 * HW];
    }

#pragma unroll
    for (int p = 0; p < 8; ++p) {
        const float frr = frs[r * 8 + p],   fir = fis[r * 8 + p];
        const float frc = frs[col * 8 + p], fic = fis[col * 8 + p];
        {
            float a = q[3*p], b = q[3*p+1], c3 = q[3*p+2];
            float b2 = a * fir + b * frr;
            q[3*p]   = a * frr - b * fir;
            q[3*p+1] = b2 * frc - c3 * fic;
            q[3*p+2] = b2 * fic + c3 * frc;
        }
        {
            float a = k[3*p], b = k[3*p+1], c3 = k[3*p+2];
            float b2 = a * fir + b * frr;
            k[3*p]   = a * frr - b * fir;
            k[3*p+1] = b2 * frc - c3 * fic;
            k[3*p+2] = b2 * fic + c3 * frc;
        }
    }

    // raw region fully consumed into regs above; fragments may overwrite it
    asm volatile("" ::: "memory");
    {
        // log2(e)/sqrt(24): folds the exp->exp2 conversion into the Q scale
        const float sc = 0.29448903f;
        uint2* qw = (uint2*)&uld[QO + lane * 12];
        uint2* kw = (uint2*)&uld[KO + lane * 12];
#pragma unroll
        for (int j = 0; j < 3; ++j) {
            qw[2*j]   = make_uint2(h2u(pk2(q[8*j]*sc,   q[8*j+1]*sc)),
                                   h2u(pk2(q[8*j+2]*sc, q[8*j+3]*sc)));
            qw[2*j+1] = make_uint2(h2u(pk2(q[8*j+4]*sc, q[8*j+5]*sc)),
                                   h2u(pk2(q[8*j+6]*sc, q[8*j+7]*sc)));
            kw[2*j]   = make_uint2(h2u(pk2(k[8*j],   k[8*j+1])),
                                   h2u(pk2(k[8*j+2], k[8*j+3])));
            kw[2*j+1] = make_uint2(h2u(pk2(k[8*j+4], k[8*j+5])),
                                   h2u(pk2(k[8*j+6], k[8*j+7])));
        }
    }
    {
#pragma unroll
        for (int i = 0; i < 5; ++i) {           // zero V^T rows 24..31
            int idx = lane + i * 64;
            if (idx < 288) uld[VTO + 24 * 36 + idx] = 0;
        }
        __fp16* vt = (__fp16*)&uld[VTO];
        vt[24 * 72 + lane] = (__fp16)1.0f;      // ones row -> denominators
#pragma unroll
        for (int dd = 0; dd < 24; ++dd) vt[dd * 72 + lane] = (__fp16)v[dd];
    }
    asm volatile("" ::: "memory");

    // ---- phase 2 ----
    const int qq = lane >> 4, l15 = lane & 15;
    v8h Qf[4], Kf[4];
#pragma unroll
    for (int t = 0; t < 4; ++t) {
        const unsigned* qa = (qq < 3) ? &uld[QO + (16*t + l15)*12 + 4*qq] : zblk;
        const unsigned* ka = (qq < 3) ? &uld[KO + (16*t + l15)*12 + 4*qq] : zblk;
        Qf[t] = as_v8h(*(const uint4*)qa);
        Kf[t] = as_v8h(*(const uint4*)ka);
    }
    v8h Vf[2][2];
#pragma unroll
    for (int dt = 0; dt < 2; ++dt)
#pragma unroll
        for (int ks = 0; ks < 2; ++ks)
            Vf[dt][ks] = as_v8h(*(const uint4*)&uld[VTO + (16*dt + l15)*36 + 16*ks + 4*qq]);

    // Swapped-operand QK^T: mfma(K,Q) gives S^T -> pack exp2'd P pairs,
    // one ds_write_b64 per tile.
#pragma unroll
    for (int tn = 0; tn < 4; ++tn) {
#pragma unroll
        for (int tm = 0; tm < 4; ++tm) {
            v4f c = {0.f, 0.f, 0.f, 0.f};
            c = __builtin_amdgcn_mfma_f32_16x16x32_f16(Kf[tn], Qf[tm], c, 0, 0, 0);
            uint2 w = make_uint2(h2u(pk2(__builtin_amdgcn_exp2f(c[0]),
                                         __builtin_amdgcn_exp2f(c[1]))),
                                 h2u(pk2(__builtin_amdgcn_exp2f(c[2]),
                                         __builtin_amdgcn_exp2f(c[3]))));
            *(uint2*)&uld[PO + (16*tm + l15)*36 + 8*tn + 2*qq] = w;
        }
    }

    v4f O[2][4];
#pragma unroll
    for (int dt = 0; dt < 2; ++dt)
#pragma unroll
        for (int lt = 0; lt < 4; ++lt)
            O[dt][lt] = (v4f){0.f, 0.f, 0.f, 0.f};
#pragma unroll
    for (int lt = 0; lt < 4; ++lt) {
#pragma unroll
        for (int ks = 0; ks < 2; ++ks) {
            v8h Pf = as_v8h(*(const uint4*)&uld[PO + (16*lt + l15)*36 + 16*ks + 4*qq]);
            O[0][lt] = __builtin_amdgcn_mfma_f32_16x16x32_f16(Vf[0][ks], Pf, O[0][lt], 0, 0, 0);
            O[1][lt] = __builtin_amdgcn_mfma_f32_16x16x32_f16(Vf[1][ks], Pf, O[1][lt], 0, 0, 0);
        }
    }

    float inv[4];
#pragma unroll
    for (int lt = 0; lt < 4; ++lt)
        inv[lt] = 1.0f / __shfl(O[1][lt][0], 32 + l15, 64);

    if (wsP) {
        // Pixel-major epilogue (R15-verified): LDS-stage sm[pixel][dp], then
        // lane = pixel writes 48B (3x uint4) -> 384B row-runs.
        unsigned* sm = uld;
        asm volatile("" ::: "memory");
#pragma unroll
        for (int lt = 0; lt < 4; ++lt) {
            const int   l  = 16*lt + l15;
            const float sc = inv[lt];
            sm[l*12 + 2*qq]     = h2u(pk2(O[0][lt][0]*sc, O[0][lt][1]*sc));
            sm[l*12 + 2*qq + 1] = h2u(pk2(O[0][lt][2]*sc, O[0][lt][3]*sc));
            if (qq < 2) {
                sm[l*12 + 8 + 2*qq] = h2u(pk2(O[1][lt][0]*sc, O[1][lt][1]*sc));
                sm[l*12 + 9 + 2*qq] = h2u(pk2(O[1][lt][2]*sc, O[1][lt][3]*sc));
            }
        }
        asm volatile("" ::: "memory");
        const int goffh = (g & 1) ? 6 : 0, goffw = (g & 2) ? 6 : 0;
        const int oh = ih * 12 + (lane >> 3) + goffh;
        const int ow = iw * 12 + (lane & 7)  + goffw;
        if (oh < HDIM && ow < HDIM) {
            uint4* dst = (uint4*)&wsP[((size_t)(g * 8 + head) * HW
                                       + (size_t)oh * HDIM + ow) * 12];
            const uint4* src = (const uint4*)&sm[lane * 12];
            dst[0] = src[0]; dst[1] = src[1]; dst[2] = src[2];
        }
    } else {
        // atomic fallback
#pragma unroll
        for (int lt = 0; lt < 4; ++lt) {
            const int l  = 16*lt + l15;
            const int oh = ih * 12 + (l >> 3) + ((g & 1) ? 6 : 0);
            const int ow = iw * 12 + (l & 7)  + ((g & 2) ? 6 : 0);
            if (oh < HDIM && ow < HDIM) {
                const float sc = inv[lt] / wgt[oh * HDIM + ow];
                float* ob = out + (size_t)(head * 24) * HW + oh * HDIM + ow;
#pragma unroll
                for (int rg = 0; rg < 4; ++rg)
                    atomicAdd(ob + (size_t)(4*qq + rg) * HW, O[0][lt][rg] * sc);
                if (qq < 2) {
#pragma unroll
                    for (int rg = 0; rg < 4; ++rg)
                        atomicAdd(ob + (size_t)(16 + 4*qq + rg) * HW, O[1][lt][rg] * sc);
                }
            }
        }
    }
}

// ---- phase B: overlap-add merge (R15-verified). Thread = (head, pixel). ----
__global__ __launch_bounds__(256)
void merge_out(const unsigned* __restrict__ wsP,
               const float* __restrict__ wgt,
               float* __restrict__ out)
{
    const int idx  = blockIdx.x * 256 + threadIdx.x;   // grid exact: 8*HW
    const int head = idx / HW;
    const int pix  = idx - head * HW;
    const int h    = pix / HDIM;
    const int w    = pix - h * HDIM;

    float acc[24];
#pragma unroll
    for (int d = 0; d < 24; ++d) acc[d] = 0.f;

#pragma unroll
    for (int g = 0; g < 4; ++g) {
        const int hh = h - ((g & 1) ? 6 : 0);
        const int ww = w - ((g & 2) ? 6 : 0);
        if (hh < 0 || ww < 0) continue;
        if (hh % 12 >= 8 || ww % 12 >= 8) continue;
        const uint4* src = (const uint4*)&wsP[((size_t)(g * 8 + head) * HW + pix) * 12];
#pragma unroll
        for (int j = 0; j < 3; ++j) {
            const uint4 u = src[j];
#pragma unroll
            for (int t = 0; t < 4; ++t) {
                const h2 p = u2h(((const unsigned*)&u)[t]);
                acc[8*j + 2*t]     += (float)p[0];
                acc[8*j + 2*t + 1] += (float)p[1];
            }
        }
    }
    const float wv = wgt[pix];
#pragma unroll
    for (int d = 0; d < 24; ++d)
        out[(size_t)(head * 24 + d) * HW + pix] = acc[d] / wv;
}

extern "C" void kernel_launch(void* const* d_in, const int* in_sizes, int n_in,
                              void* d_out, int out_size, void* d_ws, size_t ws_size,
                              hipStream_t stream) {
    const float* x   = (const float*)d_in[0];
    const float* fc  = (const float*)d_in[1];
    const float* wgt = (const float*)d_in[2];
    float* out = (float*)d_out;

    unsigned* wsP = ws_size >= P_BYTES ? (unsigned*)d_ws : nullptr;

    if (!wsP)
        (void)hipMemsetAsync(out, 0, (size_t)out_size * sizeof(float), stream);
    attn_mfma<<<NUNITS, 64, 0, stream>>>(x, fc, wgt, out, wsP);
    if (wsP)
        merge_out<<<8 * HW / 256, 256, 0, stream>>>(wsP, wgt, out);
}